// Round 7
// baseline (2118.374 us; speedup 1.0000x reference)
//
#include <hip/hip_runtime.h>
#include <hip/hip_bf16.h>
#include <stdint.h>

using bf16 = __hip_bfloat16;
typedef __bf16 bf16x8 __attribute__((ext_vector_type(8)));
typedef float f32x4 __attribute__((ext_vector_type(4)));
typedef unsigned short u16x8 __attribute__((ext_vector_type(8)));

#define GLOAD_LDS16(gp, lp)                                                    \
  __builtin_amdgcn_global_load_lds(                                           \
      (const __attribute__((address_space(1))) void*)(gp),                     \
      (__attribute__((address_space(3))) void*)(lp), 16, 0, 0)

#define WAITCNT_VM0() asm volatile("s_waitcnt vmcnt(0)" ::: "memory")
#define WAITCNT_VM6() asm volatile("s_waitcnt vmcnt(6)" ::: "memory")
#define WAITCNT_VM8() asm volatile("s_waitcnt vmcnt(8)" ::: "memory")
#define WAITCNT_LGKM0() asm volatile("s_waitcnt lgkmcnt(0)" ::: "memory")
#define CFENCE() asm volatile("" ::: "memory")
#define BAR() do { CFENCE(); __builtin_amdgcn_s_barrier(); CFENCE(); } while (0)

__device__ inline void store_out(bf16* p, float v)  { *p = __float2bfloat16(v); }
__device__ inline void store_out(float* p, float v) { *p = v; }

// 16 MFMA for one C-quadrant (QM,QN) over K=64.
template <int QM, int QN>
__device__ __forceinline__ void mfma_q(f32x4 (&acc)[8][4],
                                       const bf16x8 (&AV)[4][2],
                                       const bf16x8 (&BV)[2][2])
{
    #pragma unroll
    for (int kk = 0; kk < 2; ++kk)
        #pragma unroll
        for (int mf = 0; mf < 4; ++mf)
            #pragma unroll
            for (int nf = 0; nf < 2; ++nf)
                acc[QM * 4 + mf][QN * 2 + nf] =
                    __builtin_amdgcn_mfma_f32_16x16x32_bf16(
                        AV[mf][kk], BV[nf][kk],
                        acc[QM * 4 + mf][QN * 2 + nf], 0, 0, 0);
}

// ---------------------------------------------------------------------------
// NT GEMM, 256x256 tile, BK=64, 2-deep LDS dbuf (128 KB), READ-AHEAD pipeline:
// fragment ds_reads for phase p+1 are issued right after phase p's MFMA
// cluster, so the 8-wave LDS backlog drains UNDER the MFMA window and the
// top-of-phase lgkmcnt(0) is nearly free. ONE barrier per phase (safety: half
// X's reads drain at each wave's top-of-phase lgkm0, which precedes that
// phase's barrier; stages of X are issued post-barrier).
// Quadrant order per tile: (0,0)(0,1)(1,0)(1,1); reads: end-q11'(prev tile):
// A0+B0 (12), end-q00: B1 (4), end-q01: A1 (8), end-q10: none.
// Stages (tile T stages T+2 into same buf): q01: B-half0, q10: B-half1 +
// A-half0, q11: A-half1. WAR windows verified per half (tightest: B-half0
// last-read-issue end-q00, drained lgkm+BAR before its q01 stage).
// vmcnt(6) at q11-top (steady: 8 older + 6 newer outstanding -> drain tile
// T+1), vmcnt(0) at q11(nk-2); prologue stages tiles 0,1 (16 loads)+vmcnt(8).
// LDS swizzle (T2, 0 conflicts measured): chunk row r, 16B-col c stored at
// c ^ (r&7); read col = (kk*4+c16) ^ (fr&7).  T1 chunked XCD swizzle (NFAST).
// 512 thr = 8 waves (2Mx4N), per-wave 128x64 out. Col-split epilogue.
// M,N mult of 256; K mult of 128, K/64 >= 4.
// ---------------------------------------------------------------------------
template <typename OUT_T, int BIAS_AXIS, bool NFAST>
__global__ __launch_bounds__(512, 2) void gemm256(
    const bf16* __restrict__ A, const bf16* __restrict__ Bt,
    const float* __restrict__ bias0, const float* __restrict__ bias1,
    OUT_T* __restrict__ out0, OUT_T* __restrict__ out1, int Nsplit,
    int K, int lda, int ldb, int ldc,
    long long sA, long long sB, long long sC, float alpha)
{
    __shared__ __align__(16) bf16 lds[65536];   // 128 KB

    // T1 chunked XCD swizzle + logical tile decode
    const int Mt = gridDim.x, Nt = gridDim.y;
    const int nwg = Mt * Nt * gridDim.z;
    const int hw  = blockIdx.x + Mt * (blockIdx.y + Nt * blockIdx.z);
    const int lg  = (nwg & 7) ? hw : ((hw & 7) * (nwg >> 3) + (hw >> 3));
    const int per = Mt * Nt;
    const int zt  = lg / per;
    const int rem = lg - zt * per;
    int mt, ntile;
    if (NFAST) { mt = rem / Nt; ntile = rem - mt * Nt; }
    else       { mt = rem % Mt; ntile = rem / Mt; }

    A  += (long long)zt * sA;
    Bt += (long long)zt * sB;
    out0 += (long long)zt * sC;
    if (out1) out1 += (long long)zt * sC;

    const int bm = mt * 256, bn = ntile * 256;
    const int t = threadIdx.x, lane = t & 63;
    const int w = t >> 6, wm = w >> 2, wn = w & 3;
    const int fr = lane & 15, c16 = lane >> 4;

    // staging: thread t stages chunks t and t+512 of each 128x64 half-tile
    const int sr  = t >> 3;                         // row 0..63 (and +64)
    const int scc = ((t & 7) ^ (sr & 7)) << 3;      // pre-swizzled src col
    const bf16* pA = A  + (long long)(bm + sr) * lda + scc;
    const bf16* pB = Bt + (long long)(bn + sr) * ldb + scc;
    const int ldst = t * 8;                         // dst elem in half

#define STAGE_A(HALF, JT, BUFO) do {                                           \
    const bf16* _s = pA + (long long)(HALF) * 128 * lda + (JT) * 64;           \
    GLOAD_LDS16(_s, &lds[(BUFO) + (HALF) * 8192 + ldst]);                      \
    GLOAD_LDS16(_s + 64 * (long long)lda,                                      \
                &lds[(BUFO) + (HALF) * 8192 + ldst + 4096]);                   \
} while (0)
#define STAGE_B(HALF, JT, BUFO) do {                                           \
    const bf16* _s = pB + (long long)(HALF) * 128 * ldb + (JT) * 64;           \
    GLOAD_LDS16(_s, &lds[(BUFO) + 16384 + (HALF) * 8192 + ldst]);              \
    GLOAD_LDS16(_s + 64 * (long long)ldb,                                      \
                &lds[(BUFO) + 16384 + (HALF) * 8192 + ldst + 4096]);           \
} while (0)

    // fragment read addressing (swizzled)
    const int axor0 = ((c16    ) ^ (fr & 7)) << 3;  // kk=0
    const int axor1 = ((c16 + 4) ^ (fr & 7)) << 3;  // kk=1
    const int aoffc = wm * 8192 + fr * 64;
    const int boffc = 16384 + (wn * 64 + fr) * 64;

#define RD(e) (*reinterpret_cast<const bf16x8*>(&lds[(e)]))
#define READ_AQ(DST, QM, BUFO) do {                                            \
    _Pragma("unroll") for (int mf = 0; mf < 4; ++mf) {                         \
        DST[mf][0] = RD((BUFO) + aoffc + (QM) * 4096 + mf * 1024 + axor0);     \
        DST[mf][1] = RD((BUFO) + aoffc + (QM) * 4096 + mf * 1024 + axor1);     \
    } } while (0)
#define READ_BQ(DST, QN, BUFO) do {                                            \
    _Pragma("unroll") for (int nf = 0; nf < 2; ++nf) {                         \
        DST[nf][0] = RD((BUFO) + boffc + (QN) * 2048 + nf * 1024 + axor0);     \
        DST[nf][1] = RD((BUFO) + boffc + (QN) * 2048 + nf * 1024 + axor1);     \
    } } while (0)

    const int nkt = K >> 6;          // K-tiles of 64 (even, >= 4)
    const int half_iters = nkt >> 1;

    f32x4 acc[8][4] = {};
    bf16x8 aA0[4][2], aA1[4][2], bB0[2][2], bB1[2][2];

    // prologue: stage tiles 0 (buf0) and 1 (buf1) fully; drain tile 0; preread
    STAGE_A(0, 0, 0); STAGE_A(1, 0, 0); STAGE_B(0, 0, 0); STAGE_B(1, 0, 0);
    STAGE_A(0, 1, 32768); STAGE_A(1, 1, 32768);
    STAGE_B(0, 1, 32768); STAGE_B(1, 1, 32768);
    WAITCNT_VM8();
    BAR();
    READ_AQ(aA0, 0, 0); READ_BQ(bB0, 0, 0);

    // one tile = 4 single-barrier phases; STG/RDN are compile-time 0/1
#define TILE4(BUFO, NBUFO, JT, STG, VMQ, RDN) do {                             \
    /* q00 */                                                                  \
    WAITCNT_LGKM0(); __builtin_amdgcn_sched_barrier(0);                        \
    BAR();                                                                     \
    __builtin_amdgcn_s_setprio(1); mfma_q<0, 0>(acc, aA0, bB0);                \
    __builtin_amdgcn_s_setprio(0);                                             \
    READ_BQ(bB1, 1, BUFO);                                                     \
    /* q01 */                                                                  \
    WAITCNT_LGKM0(); __builtin_amdgcn_sched_barrier(0);                        \
    BAR();                                                                     \
    if (STG) STAGE_B(0, JT, BUFO);                                             \
    __builtin_amdgcn_s_setprio(1); mfma_q<0, 1>(acc, aA0, bB1);                \
    __builtin_amdgcn_s_setprio(0);                                             \
    READ_AQ(aA1, 1, BUFO);                                                     \
    /* q10 */                                                                  \
    WAITCNT_LGKM0(); __builtin_amdgcn_sched_barrier(0);                        \
    BAR();                                                                     \
    if (STG) { STAGE_B(1, JT, BUFO); STAGE_A(0, JT, BUFO); }                   \
    __builtin_amdgcn_s_setprio(1); mfma_q<1, 0>(acc, aA1, bB0);                \
    __builtin_amdgcn_s_setprio(0);                                             \
    /* q11 */                                                                  \
    WAITCNT_LGKM0(); __builtin_amdgcn_sched_barrier(0);                        \
    VMQ;                                                                       \
    BAR();                                                                     \
    if (STG) STAGE_A(1, JT, BUFO);                                             \
    __builtin_amdgcn_s_setprio(1); mfma_q<1, 1>(acc, aA1, bB1);                \
    __builtin_amdgcn_s_setprio(0);                                             \
    if (RDN) { READ_AQ(aA0, 0, NBUFO); READ_BQ(bB0, 0, NBUFO); }               \
} while (0)

    for (int tp = 0; tp < half_iters; ++tp) {
        if (tp + 1 < half_iters) {
            const int jt0 = 2 * tp + 2, jt1 = 2 * tp + 3;
            TILE4(0,     32768, jt0, 1, WAITCNT_VM6(), 1);
            TILE4(32768, 0,     jt1, 1, WAITCNT_VM6(), 1);
        } else {
            TILE4(0,     32768, 0, 0, WAITCNT_VM0(), 1);
            TILE4(32768, 0,     0, 0, (void)0,       0);
        }
    }

    // ---- epilogue: C/D layout col = lane&15, row = 4*(lane>>4)+reg
    const int colbase = bn + wn * 64 + fr;
    const int rowbase = bm + wm * 128 + c16 * 4;
    #pragma unroll
    for (int n = 0; n < 4; ++n) {
        const int gc = colbase + n * 16;
        const bool seg0 = gc < Nsplit;
        OUT_T* op = seg0 ? out0 : out1;
        const int col = seg0 ? gc : gc - Nsplit;
        float bcol = 0.0f;
        if (BIAS_AXIS == 0) {
            const float* bp = seg0 ? bias0 : bias1;
            if (bp) bcol = bp[col];
        }
        #pragma unroll
        for (int m = 0; m < 8; ++m) {
            #pragma unroll
            for (int jj = 0; jj < 4; ++jj) {
                const int row = rowbase + m * 16 + jj;
                float v = acc[m][n][jj] * alpha;
                if (BIAS_AXIS == 0) v += bcol;
                else if (bias0)     v += bias0[row];
                store_out(&op[(long long)row * ldc + col], v);
            }
        }
    }
#undef STAGE_A
#undef STAGE_B
#undef RD
#undef READ_AQ
#undef READ_BQ
#undef TILE4
}

// ---------------------------------------------------------------------------
__global__ __launch_bounds__(256) void f32_to_bf16(
    const float* __restrict__ in, bf16* __restrict__ out, long long n)
{
    long long i = ((long long)blockIdx.x * 256 + threadIdx.x) * 4;
    const long long stride = (long long)gridDim.x * 256 * 4;
    for (; i < n; i += stride) {
        float4 v = *reinterpret_cast<const float4*>(in + i);
        unsigned ux = __float_as_uint(v.x), uy = __float_as_uint(v.y);
        unsigned uz = __float_as_uint(v.z), uw = __float_as_uint(v.w);
        ushort4 o;
        o.x = (unsigned short)((ux + 0x7fffu + ((ux >> 16) & 1u)) >> 16);
        o.y = (unsigned short)((uy + 0x7fffu + ((uy >> 16) & 1u)) >> 16);
        o.z = (unsigned short)((uz + 0x7fffu + ((uz >> 16) & 1u)) >> 16);
        o.w = (unsigned short)((uw + 0x7fffu + ((uw >> 16) & 1u)) >> 16);
        *reinterpret_cast<ushort4*>(out + i) = o;
    }
}

__global__ void transpose_f32_bf16(const float* __restrict__ in,
                                   bf16* __restrict__ out, int R, int C)
{
    __shared__ float tile[32][33];
    const int c0 = blockIdx.x * 32, r0 = blockIdx.y * 32;
    const int tx = threadIdx.x, ty = threadIdx.y;
    #pragma unroll
    for (int i = ty; i < 32; i += 8)
        tile[i][tx] = in[(long long)(r0 + i) * C + (c0 + tx)];
    __syncthreads();
    #pragma unroll
    for (int i = ty; i < 32; i += 8)
        out[(long long)(c0 + i) * R + (r0 + tx)] = __float2bfloat16(tile[tx][i]);
}

__global__ __launch_bounds__(256) void softmax_rows(bf16* __restrict__ Sbuf, int cols)
{
    __shared__ float red[8];
    bf16* p = Sbuf + (long long)blockIdx.x * cols;
    const int t = threadIdx.x;

    u16x8 v = *reinterpret_cast<const u16x8*>(p + t * 8);
    float f[8];
    #pragma unroll
    for (int i = 0; i < 8; ++i)
        f[i] = __uint_as_float((unsigned)v[i] << 16);

    float m = -3.0e38f;
    #pragma unroll
    for (int i = 0; i < 8; ++i) m = fmaxf(m, f[i]);
    #pragma unroll
    for (int o = 32; o; o >>= 1) m = fmaxf(m, __shfl_xor(m, o));
    if ((t & 63) == 0) red[t >> 6] = m;
    __syncthreads();
    m = fmaxf(fmaxf(red[0], red[1]), fmaxf(red[2], red[3]));

    float s = 0.0f;
    #pragma unroll
    for (int i = 0; i < 8; ++i) { f[i] = __expf(f[i] - m); s += f[i]; }
    #pragma unroll
    for (int o = 32; o; o >>= 1) s += __shfl_xor(s, o);
    __syncthreads();
    if ((t & 63) == 0) red[4 + (t >> 6)] = s;
    __syncthreads();
    s = (red[4] + red[5]) + (red[6] + red[7]);
    const float inv = 1.0f / s;

    u16x8 o16;
    #pragma unroll
    for (int i = 0; i < 8; ++i) {
        unsigned u = __float_as_uint(f[i] * inv);
        o16[i] = (unsigned short)((u + 0x7fffu + ((u >> 16) & 1u)) >> 16);  // RNE
    }
    *reinterpret_cast<u16x8*>(p + t * 8) = o16;
}

// ---------------------------------------------------------------------------
extern "C" void kernel_launch(void* const* d_in, const int* in_sizes, int n_in,
                              void* d_out, int out_size, void* d_ws, size_t ws_size,
                              hipStream_t stream)
{
    const int B = 8, S = 2048, D = 1024, H = 1024;
    const float* x  = (const float*)d_in[0];
    const float* Wq = (const float*)d_in[1];
    const float* bq = (const float*)d_in[2];
    const float* Wk = (const float*)d_in[3];
    const float* bk = (const float*)d_in[4];
    const float* Wv = (const float*)d_in[5];
    const float* bv = (const float*)d_in[6];
    float* out = (float*)d_out;

    const size_t nQKV = (size_t)B * S * H;
    const size_t nW   = (size_t)D * H;
    const long long sSH = (long long)S * H;
    const long long sSS = (long long)S * S;

    dim3 tb(32, 8), g256(256), g512(512);
    const float inv_scale = 1.0f / 32.0f;

    bf16* xb   = (bf16*)d_ws;
    bf16* Q    = xb  + nQKV;
    bf16* Kb   = Q   + nQKV;
    bf16* Vt   = Kb  + nQKV;                 // [H][B*S]
    bf16* WtQK = Vt  + nQKV;
    bf16* Wtv  = WtQK + 2 * nW;
    bf16* Sc   = Wtv + nW;

    const size_t tierA = (4 * nQKV + 3 * nW + (size_t)B * S * S) * 2;
    const size_t tierB = (4 * nQKV + 3 * nW + (size_t)S * S) * 2;
    const bool bigA = ws_size >= tierA;
    if (ws_size < tierB) return;

    f32_to_bf16<<<dim3(2048), g256, 0, stream>>>(x, xb, (long long)nQKV);
    transpose_f32_bf16<<<dim3(H / 32, D / 32), tb, 0, stream>>>(Wq, WtQK, D, H);
    transpose_f32_bf16<<<dim3(H / 32, D / 32), tb, 0, stream>>>(Wk, WtQK + nW, D, H);
    transpose_f32_bf16<<<dim3(H / 32, D / 32), tb, 0, stream>>>(Wv, Wtv, D, H);

    // fused Q|K projection
    gemm256<bf16, 0, true><<<dim3(B * S / 256, 2 * H / 256, 1), g512, 0, stream>>>(
        xb, WtQK, bq, bk, Q, Kb, H, D, D, D, H, 0, 0, 0, 1.0f);

    // V^T = Wv^T x^T (bias per-row)
    gemm256<bf16, 1, false><<<dim3(H / 256, B * S / 256, 1), g512, 0, stream>>>(
        Wtv, xb, bv, nullptr, Vt, nullptr, 1 << 30, D, D, D, B * S, 0, 0, 0, 1.0f);

    if (bigA) {
        gemm256<bf16, 0, true><<<dim3(S / 256, S / 256, B), g512, 0, stream>>>(
            Q, Kb, nullptr, nullptr, Sc, nullptr, 1 << 30, H, H, H, S,
            sSH, sSH, sSS, inv_scale);
        softmax_rows<<<dim3(B * S), g256, 0, stream>>>(Sc, S);
        gemm256<float, 0, true><<<dim3(S / 256, H / 256, B), g512, 0, stream>>>(
            Sc, Vt, nullptr, nullptr, out, nullptr, 1 << 30, S, S, B * S, H,
            sSS, (long long)S, sSH, 1.0f);
    } else {
        for (int b = 0; b < B; ++b) {
            gemm256<bf16, 0, true><<<dim3(S / 256, S / 256, 1), g512, 0, stream>>>(
                Q + (size_t)b * sSH, Kb + (size_t)b * sSH, nullptr, nullptr,
                Sc, nullptr, 1 << 30, H, H, H, S, 0, 0, 0, inv_scale);
            softmax_rows<<<dim3(S), g256, 0, stream>>>(Sc, S);
            gemm256<float, 0, true><<<dim3(S / 256, H / 256, 1), g512, 0, stream>>>(
                Sc, Vt + (size_t)b * S, nullptr, nullptr,
                out + (size_t)b * sSH, nullptr, 1 << 30, S, S, B * S, H,
                0, 0, 0, 1.0f);
        }
    }
}

// Round 8
// 338.828 us; speedup vs baseline: 6.2521x; 6.2521x over previous
//
#include <hip/hip_runtime.h>
#include <hip/hip_bf16.h>
#include <stdint.h>

using bf16 = __hip_bfloat16;
typedef __bf16 bf16x8 __attribute__((ext_vector_type(8)));
typedef float f32x4 __attribute__((ext_vector_type(4)));
typedef unsigned short u16x8 __attribute__((ext_vector_type(8)));

#define GLOAD_LDS16(gp, lp)                                                    \
  __builtin_amdgcn_global_load_lds(                                           \
      (const __attribute__((address_space(1))) void*)(gp),                     \
      (__attribute__((address_space(3))) void*)(lp), 16, 0, 0)

#define WAITCNT_VM(N) asm volatile("s_waitcnt vmcnt(" #N ")" ::: "memory")
#define SB0() __builtin_amdgcn_sched_barrier(0)

__device__ inline void store_out(bf16* p, float v)  { *p = __float2bfloat16(v); }
__device__ inline void store_out(float* p, float v) { *p = v; }

// ---------------------------------------------------------------------------
// NT GEMM, 256x256 tile, BK=32, 4-deep LDS ring (128 KB), counted vmcnt (T4),
// bank-swizzled LDS (T2, 0 conflicts measured), T1 chunked-XCD swizzle.
// UNSHACKLED region scheduling: one barrier per K-step; region =
// [12 ds_read_b128 + 4 global_load_lds + 32 MFMA] bounded by sched_barrier(0)
// pins; the compiler's own counted lgkmcnt waits interleave the LDS drain
// under the MFMA cluster (m97-verified behavior). No asm lgkm0 (that forced
// full drain->MFMA serialization = the ~700 TF plateau of rounds 3-6).
// Correctness:
//   RAW (stage->read): vmcnt(8)+barrier at step end => ring[j+1] resident.
//     (outstanding after step j's stage = tiles j+1,j+2,j+3 = 12 loads;
//      drain to 8 completes tile j+1. Tail: vmcnt 4 / 0.)
//   WAR (read->stage): every ds_read of ring[j] feeds an MFMA in-region, so
//     compiler-inserted waits drain it before the wave reaches the barrier;
//     stages targeting ring[j] (= slot (j+4)&3) are issued only after it.
//   sched_barrier(0) pins stop reads/stages/MFMAs crossing barriers.
// C[m][n] = alpha * sum_k A[m][k]*Bt[n][k] (+bias). 512 thr = 8 waves (2Mx4N),
// per-wave 128x64 out (8x4 frags). Col-split epilogue: cols [0,Nsplit)->out0,
// rest->out1. BIAS_AXIS: 0 per-col, 1 per-row. M,N mult 256; K mult 32, >=128.
//
// LDS chunk layout per ring slot (A: elems [0,8192), B: [8192,16384)):
//   chunk idx (0..1023): slot=idx&7, r=2*(idx>>3)+(idx&1), c16=((slot^(r&7))>>1)
//   read side: elem(r,c16) = (r>>1)*64 + ((r&7)^(c16<<1))*8   [2-way banks=free]
// ---------------------------------------------------------------------------
template <typename OUT_T, int BIAS_AXIS, bool NFAST>
__global__ __launch_bounds__(512, 2) void gemm256(
    const bf16* __restrict__ A, const bf16* __restrict__ Bt,
    const float* __restrict__ bias0, const float* __restrict__ bias1,
    OUT_T* __restrict__ out0, OUT_T* __restrict__ out1, int Nsplit,
    int K, int lda, int ldb, int ldc,
    long long sA, long long sB, long long sC, float alpha)
{
    __shared__ __align__(16) bf16 lds[4 * 16384];   // 4 ring slots x 32 KB

    // ---- T1: chunked XCD swizzle + logical tile decode
    const int Mt = gridDim.x, Nt = gridDim.y;
    const int nwg = Mt * Nt * gridDim.z;
    const int hw  = blockIdx.x + Mt * (blockIdx.y + Nt * blockIdx.z);
    const int lg  = (nwg & 7) ? hw : ((hw & 7) * (nwg >> 3) + (hw >> 3));
    const int per = Mt * Nt;
    const int zt  = lg / per;
    const int rem = lg - zt * per;
    int mt, nt;
    if (NFAST) { mt = rem / Nt; nt = rem - mt * Nt; }
    else       { mt = rem % Mt; nt = rem / Mt; }

    A  += (long long)zt * sA;
    Bt += (long long)zt * sB;
    out0 += (long long)zt * sC;
    if (out1) out1 += (long long)zt * sC;

    const int bm = mt * 256;
    const int bn = nt * 256;
    const int t = threadIdx.x, lane = t & 63, w = t >> 6;
    const int wm = w >> 2, wn = w & 3;            // wave tile coords (2 x 4)
    const int fr = lane & 15, c16 = lane >> 4;

    // ---- staging precompute: 4 chunks/thread (2 A, 2 B), inverse-swizzled src
    const bf16* gsrc[4];
    int lbase[4];
    #pragma unroll
    for (int c = 0; c < 4; ++c) {
        const int idx  = w * 128 + (c & 1) * 64 + lane;    // chunk in half
        const int slot = idx & 7;
        const int r    = ((idx >> 3) << 1) | (idx & 1);
        const int cc   = (slot ^ (r & 7)) >> 1;            // 0..3
        if (c < 2) {
            gsrc[c]  = A + (long long)(bm + r) * lda + cc * 8;
            lbase[c] = w * 1024 + c * 512;
        } else {
            gsrc[c]  = Bt + (long long)(bn + r) * ldb + cc * 8;
            lbase[c] = 8192 + w * 1024 + (c - 2) * 512;
        }
    }

    // ---- fragment read offsets (elements), swizzled
    const int sw   = ((fr & 7) ^ (c16 << 1)) * 8;
    const int offA = (wm * 64 + (fr >> 1)) * 64 + sw;          // + m*512
    const int offB = 8192 + (wn * 32 + (fr >> 1)) * 64 + sw;   // + n*512

    const int nk = K >> 5;

    auto STAGE4 = [&](int jt) {
        const int buf = (jt & 3) * 16384;
        #pragma unroll
        for (int c = 0; c < 4; ++c)
            GLOAD_LDS16(gsrc[c] + jt * 32, &lds[buf + lbase[c]]);
    };

    // prologue: stage tiles 0,1,2 (12 loads); drain tile 0 (counted)
    STAGE4(0); STAGE4(1); STAGE4(2);
    WAITCNT_VM(8);
    __builtin_amdgcn_s_barrier();

    f32x4 acc[8][4] = {};

    for (int j = 0; j < nk; ++j) {
        const int buf = (j & 3) * 16384;
        SB0();   // region open: nothing from previous step leaks in

        bf16x8 af[8], bfv[4];
        #pragma unroll
        for (int m = 0; m < 8; ++m)
            af[m] = *reinterpret_cast<const bf16x8*>(&lds[buf + offA + m * 512]);
        #pragma unroll
        for (int n = 0; n < 4; ++n)
            bfv[n] = *reinterpret_cast<const bf16x8*>(&lds[buf + offB + n * 512]);

        if (j + 3 < nk) STAGE4(j + 3);

        // 32 MFMA — compiler interleaves counted lgkm waits with the reads
        #pragma unroll
        for (int m = 0; m < 8; ++m)
            #pragma unroll
            for (int n = 0; n < 4; ++n)
                acc[m][n] = __builtin_amdgcn_mfma_f32_16x16x32_bf16(
                    af[m], bfv[n], acc[m][n], 0, 0, 0);

        SB0();   // region close: reads/MFMA can't sink below the barrier
        if (j + 3 < nk)      { WAITCNT_VM(8); }
        else if (j + 2 < nk) { WAITCNT_VM(4); }
        else if (j + 1 < nk) { WAITCNT_VM(0); }
        __builtin_amdgcn_s_barrier();
    }

    // ---- epilogue: C/D layout col = lane&15, row = 4*(lane>>4)+reg
    const int colbase = bn + wn * 64 + fr;
    const int rowbase = bm + wm * 128 + c16 * 4;
    #pragma unroll
    for (int n = 0; n < 4; ++n) {
        const int gc = colbase + n * 16;
        const bool seg0 = gc < Nsplit;
        OUT_T* op = seg0 ? out0 : out1;
        const int col = seg0 ? gc : gc - Nsplit;
        float bcol = 0.0f;
        if (BIAS_AXIS == 0) {
            const float* bp = seg0 ? bias0 : bias1;
            if (bp) bcol = bp[col];
        }
        #pragma unroll
        for (int m = 0; m < 8; ++m) {
            #pragma unroll
            for (int jj = 0; jj < 4; ++jj) {
                const int row = rowbase + m * 16 + jj;
                float v = acc[m][n][jj] * alpha;
                if (BIAS_AXIS == 0) v += bcol;
                else if (bias0)     v += bias0[row];
                store_out(&op[(long long)row * ldc + col], v);
            }
        }
    }
}

// ---------------------------------------------------------------------------
// fp32 -> bf16 elementwise convert (n multiple of 4)
// ---------------------------------------------------------------------------
__global__ __launch_bounds__(256) void f32_to_bf16(
    const float* __restrict__ in, bf16* __restrict__ out, long long n)
{
    long long i = ((long long)blockIdx.x * 256 + threadIdx.x) * 4;
    const long long stride = (long long)gridDim.x * 256 * 4;
    for (; i < n; i += stride) {
        float4 v = *reinterpret_cast<const float4*>(in + i);
        unsigned ux = __float_as_uint(v.x), uy = __float_as_uint(v.y);
        unsigned uz = __float_as_uint(v.z), uw = __float_as_uint(v.w);
        ushort4 o;
        o.x = (unsigned short)((ux + 0x7fffu + ((ux >> 16) & 1u)) >> 16);
        o.y = (unsigned short)((uy + 0x7fffu + ((uy >> 16) & 1u)) >> 16);
        o.z = (unsigned short)((uz + 0x7fffu + ((uz >> 16) & 1u)) >> 16);
        o.w = (unsigned short)((uw + 0x7fffu + ((uw >> 16) & 1u)) >> 16);
        *reinterpret_cast<ushort4*>(out + i) = o;
    }
}

// ---------------------------------------------------------------------------
// Transpose fp32 in [R][C] -> bf16 out [C][R]
// ---------------------------------------------------------------------------
__global__ void transpose_f32_bf16(const float* __restrict__ in,
                                   bf16* __restrict__ out, int R, int C)
{
    __shared__ float tile[32][33];
    const int c0 = blockIdx.x * 32, r0 = blockIdx.y * 32;
    const int tx = threadIdx.x, ty = threadIdx.y;
    #pragma unroll
    for (int i = ty; i < 32; i += 8)
        tile[i][tx] = in[(long long)(r0 + i) * C + (c0 + tx)];
    __syncthreads();
    #pragma unroll
    for (int i = ty; i < 32; i += 8)
        out[(long long)(c0 + i) * R + (r0 + tx)] = __float2bfloat16(tile[tx][i]);
}

// ---------------------------------------------------------------------------
// Row softmax, in-place on bf16 buffer, one 256-thread block per 2048-col row.
// ---------------------------------------------------------------------------
__global__ __launch_bounds__(256) void softmax_rows(bf16* __restrict__ Sbuf, int cols)
{
    __shared__ float red[8];
    bf16* p = Sbuf + (long long)blockIdx.x * cols;
    const int t = threadIdx.x;

    u16x8 v = *reinterpret_cast<const u16x8*>(p + t * 8);
    float f[8];
    #pragma unroll
    for (int i = 0; i < 8; ++i)
        f[i] = __uint_as_float((unsigned)v[i] << 16);

    float m = -3.0e38f;
    #pragma unroll
    for (int i = 0; i < 8; ++i) m = fmaxf(m, f[i]);
    #pragma unroll
    for (int o = 32; o; o >>= 1) m = fmaxf(m, __shfl_xor(m, o));
    if ((t & 63) == 0) red[t >> 6] = m;
    __syncthreads();
    m = fmaxf(fmaxf(red[0], red[1]), fmaxf(red[2], red[3]));

    float s = 0.0f;
    #pragma unroll
    for (int i = 0; i < 8; ++i) { f[i] = __expf(f[i] - m); s += f[i]; }
    #pragma unroll
    for (int o = 32; o; o >>= 1) s += __shfl_xor(s, o);
    __syncthreads();
    if ((t & 63) == 0) red[4 + (t >> 6)] = s;
    __syncthreads();
    s = (red[4] + red[5]) + (red[6] + red[7]);
    const float inv = 1.0f / s;

    u16x8 o16;
    #pragma unroll
    for (int i = 0; i < 8; ++i) {
        unsigned u = __float_as_uint(f[i] * inv);
        o16[i] = (unsigned short)((u + 0x7fffu + ((u >> 16) & 1u)) >> 16);  // RNE
    }
    *reinterpret_cast<u16x8*>(p + t * 8) = o16;
}

// ---------------------------------------------------------------------------
extern "C" void kernel_launch(void* const* d_in, const int* in_sizes, int n_in,
                              void* d_out, int out_size, void* d_ws, size_t ws_size,
                              hipStream_t stream)
{
    const int B = 8, S = 2048, D = 1024, H = 1024;
    const float* x  = (const float*)d_in[0];
    const float* Wq = (const float*)d_in[1];
    const float* bq = (const float*)d_in[2];
    const float* Wk = (const float*)d_in[3];
    const float* bk = (const float*)d_in[4];
    const float* Wv = (const float*)d_in[5];
    const float* bv = (const float*)d_in[6];
    float* out = (float*)d_out;

    const size_t nQKV = (size_t)B * S * H;
    const size_t nW   = (size_t)D * H;
    const long long sSH = (long long)S * H;
    const long long sSS = (long long)S * S;

    dim3 tb(32, 8), g256(256), g512(512);
    const float inv_scale = 1.0f / 32.0f;    // 1/sqrt(H)

    // ws: xb | Q | K | Vt | WtQK(2nW) | Wtv(nW) | Sc
    bf16* xb   = (bf16*)d_ws;
    bf16* Q    = xb  + nQKV;
    bf16* Kb   = Q   + nQKV;
    bf16* Vt   = Kb  + nQKV;                 // [H][B*S], ld = B*S
    bf16* WtQK = Vt  + nQKV;
    bf16* Wtv  = WtQK + 2 * nW;
    bf16* Sc   = Wtv + nW;

    const size_t tierA = (4 * nQKV + 3 * nW + (size_t)B * S * S) * 2;
    const size_t tierB = (4 * nQKV + 3 * nW + (size_t)S * S) * 2;
    const bool bigA = ws_size >= tierA;
    if (ws_size < tierB) return;

    // 1. convert x; transpose weights
    f32_to_bf16<<<dim3(2048), g256, 0, stream>>>(x, xb, (long long)nQKV);
    transpose_f32_bf16<<<dim3(H / 32, D / 32), tb, 0, stream>>>(Wq, WtQK, D, H);
    transpose_f32_bf16<<<dim3(H / 32, D / 32), tb, 0, stream>>>(Wk, WtQK + nW, D, H);
    transpose_f32_bf16<<<dim3(H / 32, D / 32), tb, 0, stream>>>(Wv, Wtv, D, H);

    // 2. fused Q|K projection: [B*S,1024] x [2048,1024]^T -> Q, K (col-split)
    gemm256<bf16, 0, true><<<dim3(B * S / 256, 2 * H / 256, 1), g512, 0, stream>>>(
        xb, WtQK, bq, bk, Q, Kb, H, D, D, D, H, 0, 0, 0, 1.0f);

    // 3. V^T = Wv^T x^T : A=Wtv [H][D], Bt=xb [B*S][D] -> Vt [H][B*S], bias-by-row
    gemm256<bf16, 1, false><<<dim3(H / 256, B * S / 256, 1), g512, 0, stream>>>(
        Wtv, xb, bv, nullptr, Vt, nullptr, 1 << 30, D, D, D, B * S, 0, 0, 0, 1.0f);

    if (bigA) {
        // 4. scores = Q K^T / 32, batched
        gemm256<bf16, 0, true><<<dim3(S / 256, S / 256, B), g512, 0, stream>>>(
            Q, Kb, nullptr, nullptr, Sc, nullptr, 1 << 30, H, H, H, S,
            sSH, sSH, sSS, inv_scale);
        // 5. softmax rows in place
        softmax_rows<<<dim3(B * S), g256, 0, stream>>>(Sc, S);
        // 6. out = P V
        gemm256<float, 0, true><<<dim3(S / 256, H / 256, B), g512, 0, stream>>>(
            Sc, Vt, nullptr, nullptr, out, nullptr, 1 << 30, S, S, B * S, H,
            sSS, (long long)S, sSH, 1.0f);
    } else {
        for (int b = 0; b < B; ++b) {
            gemm256<bf16, 0, true><<<dim3(S / 256, S / 256, 1), g512, 0, stream>>>(
                Q + (size_t)b * sSH, Kb + (size_t)b * sSH, nullptr, nullptr,
                Sc, nullptr, 1 << 30, H, H, H, S, 0, 0, 0, inv_scale);
            softmax_rows<<<dim3(S), g256, 0, stream>>>(Sc, S);
            gemm256<float, 0, true><<<dim3(S / 256, H / 256, 1), g512, 0, stream>>>(
                Sc, Vt + (size_t)b * S, nullptr, nullptr,
                out + (size_t)b * sSH, nullptr, 1 << 30, S, S, B * S, H,
                0, 0, 0, 1.0f);
        }
    }
}

// Round 9
// 330.626 us; speedup vs baseline: 6.4072x; 1.0248x over previous
//
#include <hip/hip_runtime.h>
#include <hip/hip_bf16.h>
#include <stdint.h>

using bf16 = __hip_bfloat16;
typedef __bf16 bf16x8 __attribute__((ext_vector_type(8)));
typedef float f32x4 __attribute__((ext_vector_type(4)));
typedef unsigned short u16x8 __attribute__((ext_vector_type(8)));

#define GLOAD_LDS16(gp, lp)                                                    \
  __builtin_amdgcn_global_load_lds(                                           \
      (const __attribute__((address_space(1))) void*)(gp),                     \
      (__attribute__((address_space(3))) void*)(lp), 16, 0, 0)

#define WAITCNT_VM(N) asm volatile("s_waitcnt vmcnt(" #N ")" ::: "memory")
#define SB0() __builtin_amdgcn_sched_barrier(0)

__device__ inline void store_out(bf16* p, float v)  { *p = __float2bfloat16(v); }
__device__ inline void store_out(float* p, float v) { *p = v; }

// ---------------------------------------------------------------------------
// NT GEMM, 256x128 tile, BK=32, ring-3 LDS (72 KB -> 2 blocks/CU), counted
// vmcnt (T4), conflict-free swizzled LDS (T2), T1 chunked-XCD swizzle.
// KEY CHANGE vs rounds 3-8 (all 1 block/CU, lockstep-serialized read/MFMA
// phases, ~700 TF): 2 independently-barriered blocks per CU overlap one
// block's LDS-read phase with the other's MFMA phase (m97/m114 mechanism),
// and the 256x128 tile has 2x the FLOP per LDS-read-byte of 256x256-8wave.
// 256 thr = 4 waves (2M x 2N), per-wave 128x64 out (8x4 frags 16x16x32).
// C[m][n] = alpha * sum_k A[m][k]*Bt[n][k] (+bias). Col-split epilogue.
// BIAS_AXIS: 0 per-col, 1 per-row. M mult 256, N mult 128, K mult 32 (>=64).
//
// LDS: 3 ring slots x 12288 elems (A 256x32 at +0, B 128x32 at +8192).
// Chunk (16B) layout: row r (64B = 4 chunks), chunk col c stored at
// c ^ ((r>>1)&3)  -> within any 16 consecutive lanes reading a frag column
// (rows fr=0..15), (parity, swz-chunk) spreads over 8 groups = 2-way = free.
// Stage side: thread t writes chunks {t+256k} linearly (dst = idx*16B, wave-
// uniform + lane*16), global src col pre-swizzled with the same involution.
// Read side: elem(r, c16) = r*32 + ((c16 ^ ((r>>1)&3))*8.
//
// Sync per step j: [reads buf j%3 (12 ds_read_b128); stage tile j+2 (6
// gload_lds); 32 MFMA; vmcnt(6); s_barrier].  RAW: at step-j end, outstanding
// = stage(j+1) 6 + stage(j+2) 6; vmcnt(6) drains stage(j+1) -> resident for
// step j+1 after the barrier (block-wide).  WAR: stage(j+2) targets slot
// (j+2)%3 = (j-1)%3, whose reads finished (consumed by step j-1 MFMAs) before
// step j-1's closing barrier; stage is issued after it.  Tail: j=nk-2 ->
// vmcnt(0), j=nk-1 -> none.  Compiler inserts counted lgkm waits for
// ds_read->MFMA (no asm lgkm0 -> no forced drain).
// ---------------------------------------------------------------------------
template <typename OUT_T, int BIAS_AXIS, bool NFAST>
__global__ __launch_bounds__(256, 2) void gemm_bm(
    const bf16* __restrict__ A, const bf16* __restrict__ Bt,
    const float* __restrict__ bias0, const float* __restrict__ bias1,
    OUT_T* __restrict__ out0, OUT_T* __restrict__ out1, int Nsplit,
    int K, int lda, int ldb, int ldc,
    long long sA, long long sB, long long sC, float alpha)
{
    __shared__ __align__(16) bf16 lds[36864];   // 72 KB: 3 x (8192 A + 4096 B)

    // ---- T1: chunked XCD swizzle + logical tile decode
    const int Mt = gridDim.x, Nt = gridDim.y;
    const int nwg = Mt * Nt * gridDim.z;
    const int hw  = blockIdx.x + Mt * (blockIdx.y + Nt * blockIdx.z);
    const int lg  = (nwg & 7) ? hw : ((hw & 7) * (nwg >> 3) + (hw >> 3));
    const int per = Mt * Nt;
    const int zt  = lg / per;
    const int rem = lg - zt * per;
    int mt, nt;
    if (NFAST) { mt = rem / Nt; nt = rem - mt * Nt; }
    else       { mt = rem % Mt; nt = rem / Mt; }

    A  += (long long)zt * sA;
    Bt += (long long)zt * sB;
    out0 += (long long)zt * sC;
    if (out1) out1 += (long long)zt * sC;

    const int bm = mt * 256;
    const int bn = nt * 128;
    const int t = threadIdx.x, lane = t & 63, w = t >> 6;
    const int wm = w >> 1, wn = w & 1;            // wave grid 2M x 2N
    const int fr = lane & 15, c16 = lane >> 4;

    // ---- staging src pointers: A chunks {t+256k, k<4}, B chunks {t+256k, k<2}
    const bf16* gA[4];
    const bf16* gB[2];
    #pragma unroll
    for (int k = 0; k < 4; ++k) {
        const int idx = t + 256 * k, r = idx >> 2, c = idx & 3;
        gA[k] = A + (long long)(bm + r) * lda + ((c ^ ((r >> 1) & 3)) << 3);
    }
    #pragma unroll
    for (int k = 0; k < 2; ++k) {
        const int idx = t + 256 * k, r = idx >> 2, c = idx & 3;
        gB[k] = Bt + (long long)(bn + r) * ldb + ((c ^ ((r >> 1) & 3)) << 3);
    }
    const int dstA = t * 8;            // + k*2048, elem offset in slot
    const int dstB = 8192 + t * 8;     // + k*2048

#define STAGE(JT, SLOTB) do {                                                  \
    GLOAD_LDS16(gA[0] + (JT) * 32, &lds[(SLOTB) + dstA]);                      \
    GLOAD_LDS16(gA[1] + (JT) * 32, &lds[(SLOTB) + dstA + 2048]);               \
    GLOAD_LDS16(gA[2] + (JT) * 32, &lds[(SLOTB) + dstA + 4096]);               \
    GLOAD_LDS16(gA[3] + (JT) * 32, &lds[(SLOTB) + dstA + 6144]);               \
    GLOAD_LDS16(gB[0] + (JT) * 32, &lds[(SLOTB) + dstB]);                      \
    GLOAD_LDS16(gB[1] + (JT) * 32, &lds[(SLOTB) + dstB + 2048]);               \
} while (0)

    // ---- fragment read offsets (elements), swizzled
    const int swz8 = (c16 ^ ((fr >> 1) & 3)) << 3;
    const int offA = (wm * 128 + fr) * 32 + swz8;          // + mf*512
    const int offB = 8192 + (wn * 64 + fr) * 32 + swz8;    // + nf*512

    const int nk = K >> 5;

    // prologue: stage tiles 0,1; drain tile 0 (keep 6 in flight)
    STAGE(0, 0); STAGE(1, 12288);
    WAITCNT_VM(6);
    __builtin_amdgcn_s_barrier();

    f32x4 acc[8][4] = {};

    int slotb = 0;
    for (int j = 0; j < nk; ++j) {
        SB0();   // region open

        bf16x8 af[8], bfv[4];
        #pragma unroll
        for (int m = 0; m < 8; ++m)
            af[m] = *reinterpret_cast<const bf16x8*>(&lds[slotb + offA + m * 512]);
        #pragma unroll
        for (int n = 0; n < 4; ++n)
            bfv[n] = *reinterpret_cast<const bf16x8*>(&lds[slotb + offB + n * 512]);

        if (j + 2 < nk) {
            int s2 = slotb + 24576; if (s2 >= 36864) s2 -= 36864;
            STAGE(j + 2, s2);
        }

        #pragma unroll
        for (int m = 0; m < 8; ++m)
            #pragma unroll
            for (int n = 0; n < 4; ++n)
                acc[m][n] = __builtin_amdgcn_mfma_f32_16x16x32_bf16(
                    af[m], bfv[n], acc[m][n], 0, 0, 0);

        SB0();   // region close
        if (j + 2 < nk)      { WAITCNT_VM(6); }
        else if (j + 1 < nk) { WAITCNT_VM(0); }
        __builtin_amdgcn_s_barrier();

        slotb += 12288; if (slotb == 36864) slotb = 0;
    }

    // ---- epilogue: C/D layout col = lane&15, row = 4*(lane>>4)+reg
    const int colbase = bn + wn * 64 + fr;
    const int rowbase = bm + wm * 128 + c16 * 4;
    #pragma unroll
    for (int n = 0; n < 4; ++n) {
        const int gc = colbase + n * 16;
        const bool seg0 = gc < Nsplit;
        OUT_T* op = seg0 ? out0 : out1;
        const int col = seg0 ? gc : gc - Nsplit;
        float bcol = 0.0f;
        if (BIAS_AXIS == 0) {
            const float* bp = seg0 ? bias0 : bias1;
            if (bp) bcol = bp[col];
        }
        #pragma unroll
        for (int m = 0; m < 8; ++m) {
            #pragma unroll
            for (int jj = 0; jj < 4; ++jj) {
                const int row = rowbase + m * 16 + jj;
                float v = acc[m][n][jj] * alpha;
                if (BIAS_AXIS == 0) v += bcol;
                else if (bias0)     v += bias0[row];
                store_out(&op[(long long)row * ldc + col], v);
            }
        }
    }
#undef STAGE
}

// ---------------------------------------------------------------------------
// fp32 -> bf16 elementwise convert (n multiple of 4)
// ---------------------------------------------------------------------------
__global__ __launch_bounds__(256) void f32_to_bf16(
    const float* __restrict__ in, bf16* __restrict__ out, long long n)
{
    long long i = ((long long)blockIdx.x * 256 + threadIdx.x) * 4;
    const long long stride = (long long)gridDim.x * 256 * 4;
    for (; i < n; i += stride) {
        float4 v = *reinterpret_cast<const float4*>(in + i);
        unsigned ux = __float_as_uint(v.x), uy = __float_as_uint(v.y);
        unsigned uz = __float_as_uint(v.z), uw = __float_as_uint(v.w);
        ushort4 o;
        o.x = (unsigned short)((ux + 0x7fffu + ((ux >> 16) & 1u)) >> 16);
        o.y = (unsigned short)((uy + 0x7fffu + ((uy >> 16) & 1u)) >> 16);
        o.z = (unsigned short)((uz + 0x7fffu + ((uz >> 16) & 1u)) >> 16);
        o.w = (unsigned short)((uw + 0x7fffu + ((uw >> 16) & 1u)) >> 16);
        *reinterpret_cast<ushort4*>(out + i) = o;
    }
}

// ---------------------------------------------------------------------------
// Transpose fp32 in [R][C] -> bf16 out [C][R]
// ---------------------------------------------------------------------------
__global__ void transpose_f32_bf16(const float* __restrict__ in,
                                   bf16* __restrict__ out, int R, int C)
{
    __shared__ float tile[32][33];
    const int c0 = blockIdx.x * 32, r0 = blockIdx.y * 32;
    const int tx = threadIdx.x, ty = threadIdx.y;
    #pragma unroll
    for (int i = ty; i < 32; i += 8)
        tile[i][tx] = in[(long long)(r0 + i) * C + (c0 + tx)];
    __syncthreads();
    #pragma unroll
    for (int i = ty; i < 32; i += 8)
        out[(long long)(c0 + i) * R + (r0 + tx)] = __float2bfloat16(tile[tx][i]);
}

// ---------------------------------------------------------------------------
// Row softmax, in-place on bf16 buffer, one 256-thread block per 2048-col row.
// ---------------------------------------------------------------------------
__global__ __launch_bounds__(256) void softmax_rows(bf16* __restrict__ Sbuf, int cols)
{
    __shared__ float red[8];
    bf16* p = Sbuf + (long long)blockIdx.x * cols;
    const int t = threadIdx.x;

    u16x8 v = *reinterpret_cast<const u16x8*>(p + t * 8);
    float f[8];
    #pragma unroll
    for (int i = 0; i < 8; ++i)
        f[i] = __uint_as_float((unsigned)v[i] << 16);

    float m = -3.0e38f;
    #pragma unroll
    for (int i = 0; i < 8; ++i) m = fmaxf(m, f[i]);
    #pragma unroll
    for (int o = 32; o; o >>= 1) m = fmaxf(m, __shfl_xor(m, o));
    if ((t & 63) == 0) red[t >> 6] = m;
    __syncthreads();
    m = fmaxf(fmaxf(red[0], red[1]), fmaxf(red[2], red[3]));

    float s = 0.0f;
    #pragma unroll
    for (int i = 0; i < 8; ++i) { f[i] = __expf(f[i] - m); s += f[i]; }
    #pragma unroll
    for (int o = 32; o; o >>= 1) s += __shfl_xor(s, o);
    __syncthreads();
    if ((t & 63) == 0) red[4 + (t >> 6)] = s;
    __syncthreads();
    s = (red[4] + red[5]) + (red[6] + red[7]);
    const float inv = 1.0f / s;

    u16x8 o16;
    #pragma unroll
    for (int i = 0; i < 8; ++i) {
        unsigned u = __float_as_uint(f[i] * inv);
        o16[i] = (unsigned short)((u + 0x7fffu + ((u >> 16) & 1u)) >> 16);  // RNE
    }
    *reinterpret_cast<u16x8*>(p + t * 8) = o16;
}

// ---------------------------------------------------------------------------
extern "C" void kernel_launch(void* const* d_in, const int* in_sizes, int n_in,
                              void* d_out, int out_size, void* d_ws, size_t ws_size,
                              hipStream_t stream)
{
    const int B = 8, S = 2048, D = 1024, H = 1024;
    const float* x  = (const float*)d_in[0];
    const float* Wq = (const float*)d_in[1];
    const float* bq = (const float*)d_in[2];
    const float* Wk = (const float*)d_in[3];
    const float* bk = (const float*)d_in[4];
    const float* Wv = (const float*)d_in[5];
    const float* bv = (const float*)d_in[6];
    float* out = (float*)d_out;

    const size_t nQKV = (size_t)B * S * H;
    const size_t nW   = (size_t)D * H;
    const long long sSH = (long long)S * H;
    const long long sSS = (long long)S * S;

    dim3 tb(32, 8), g256(256);
    const float inv_scale = 1.0f / 32.0f;    // 1/sqrt(H)

    // ws: xb | Q | K | Vt | WtQK(2nW) | Wtv(nW) | Sc
    bf16* xb   = (bf16*)d_ws;
    bf16* Q    = xb  + nQKV;
    bf16* Kb   = Q   + nQKV;
    bf16* Vt   = Kb  + nQKV;                 // [H][B*S], ld = B*S
    bf16* WtQK = Vt  + nQKV;
    bf16* Wtv  = WtQK + 2 * nW;
    bf16* Sc   = Wtv + nW;

    const size_t tierA = (4 * nQKV + 3 * nW + (size_t)B * S * S) * 2;
    const size_t tierB = (4 * nQKV + 3 * nW + (size_t)S * S) * 2;
    const bool bigA = ws_size >= tierA;
    if (ws_size < tierB) return;

    // 1. convert x; transpose weights
    f32_to_bf16<<<dim3(2048), g256, 0, stream>>>(x, xb, (long long)nQKV);
    transpose_f32_bf16<<<dim3(H / 32, D / 32), tb, 0, stream>>>(Wq, WtQK, D, H);
    transpose_f32_bf16<<<dim3(H / 32, D / 32), tb, 0, stream>>>(Wk, WtQK + nW, D, H);
    transpose_f32_bf16<<<dim3(H / 32, D / 32), tb, 0, stream>>>(Wv, Wtv, D, H);

    // 2. fused Q|K projection: [B*S,1024] x [2048,1024]^T -> Q, K (col-split)
    gemm_bm<bf16, 0, true><<<dim3(B * S / 256, 2 * H / 128, 1), g256, 0, stream>>>(
        xb, WtQK, bq, bk, Q, Kb, H, D, D, D, H, 0, 0, 0, 1.0f);

    // 3. V^T = Wv^T x^T : A=Wtv [H][D], Bt=xb [B*S][D] -> Vt [H][B*S], bias-by-row
    gemm_bm<bf16, 1, false><<<dim3(H / 256, B * S / 128, 1), g256, 0, stream>>>(
        Wtv, xb, bv, nullptr, Vt, nullptr, 1 << 30, D, D, D, B * S, 0, 0, 0, 1.0f);

    if (bigA) {
        // 4. scores = Q K^T / 32, batched
        gemm_bm<bf16, 0, true><<<dim3(S / 256, S / 128, B), g256, 0, stream>>>(
            Q, Kb, nullptr, nullptr, Sc, nullptr, 1 << 30, H, H, H, S,
            sSH, sSH, sSS, inv_scale);
        // 5. softmax rows in place
        softmax_rows<<<dim3(B * S), g256, 0, stream>>>(Sc, S);
        // 6. out = P V
        gemm_bm<float, 0, true><<<dim3(S / 256, H / 128, B), g256, 0, stream>>>(
            Sc, Vt, nullptr, nullptr, out, nullptr, 1 << 30, S, S, B * S, H,
            sSS, (long long)S, sSH, 1.0f);
    } else {
        for (int b = 0; b < B; ++b) {
            gemm_bm<bf16, 0, true><<<dim3(S / 256, S / 128, 1), g256, 0, stream>>>(
                Q + (size_t)b * sSH, Kb + (size_t)b * sSH, nullptr, nullptr,
                Sc, nullptr, 1 << 30, H, H, H, S, 0, 0, 0, inv_scale);
            softmax_rows<<<dim3(S), g256, 0, stream>>>(Sc, S);
            gemm_bm<float, 0, true><<<dim3(S / 256, H / 128, 1), g256, 0, stream>>>(
                Sc, Vt + (size_t)b * S, nullptr, nullptr,
                out + (size_t)b * sSH, nullptr, 1 << 30, S, S, B * S, H,
                0, 0, 0, 1.0f);
        }
    }
}